// Round 3
// baseline (1304.652 us; speedup 1.0000x reference)
//
#include <hip/hip_runtime.h>
#include <hip/hip_bf16.h>
#include <math.h>

#define HID 256

typedef __attribute__((ext_vector_type(4))) float f32x4;
typedef __attribute__((ext_vector_type(8))) short bf16x8;

static __device__ __forceinline__ unsigned short bftrunc(float v) {
    return (unsigned short)(__float_as_uint(v) >> 16);
}
static __device__ __forceinline__ unsigned short bfrtne(float v) {
    unsigned u = __float_as_uint(v);
    unsigned r = u + 0x7FFFu + ((u >> 16) & 1u);
    return (unsigned short)(r >> 16);
}
static __device__ __forceinline__ float bf2f(unsigned short s) {
    return __uint_as_float(((unsigned)s) << 16);
}

// ---------------------------------------------------------------- edge prep

__global__ void hist_kernel(const int* __restrict__ dst, int* __restrict__ deg, int E) {
    int e = blockIdx.x * blockDim.x + threadIdx.x;
    if (e < E) atomicAdd(&deg[dst[e]], 1);
}

// two-level scan: scan1 (per-block inclusive) -> scan2 (scan block sums) -> scan3 (finalize)
__global__ __launch_bounds__(256) void scan1_kernel(const int* __restrict__ deg,
        int* __restrict__ incl, int* __restrict__ bsum, int N) {
    __shared__ int s[256];
    int i = blockIdx.x * 256 + threadIdx.x;
    int v = (i < N) ? deg[i] : 0;
    s[threadIdx.x] = v;
    __syncthreads();
#pragma unroll
    for (int off = 1; off < 256; off <<= 1) {
        int t = (threadIdx.x >= off) ? s[threadIdx.x - off] : 0;
        __syncthreads();
        s[threadIdx.x] += t;
        __syncthreads();
    }
    if (i < N) incl[i] = s[threadIdx.x];
    if (threadIdx.x == 255) bsum[blockIdx.x] = s[255];
}

__global__ __launch_bounds__(256) void scan2_kernel(int* __restrict__ bsum, int nb) {
    __shared__ int s[256];
    int v = (threadIdx.x < nb) ? bsum[threadIdx.x] : 0;
    s[threadIdx.x] = v;
    __syncthreads();
#pragma unroll
    for (int off = 1; off < 256; off <<= 1) {
        int t = (threadIdx.x >= off) ? s[threadIdx.x - off] : 0;
        __syncthreads();
        s[threadIdx.x] += t;
        __syncthreads();
    }
    if (threadIdx.x < nb) bsum[threadIdx.x] = s[threadIdx.x] - v;  // exclusive
}

__global__ __launch_bounds__(256) void scan3_kernel(const int* __restrict__ deg,
        const int* __restrict__ incl, const int* __restrict__ bsum,
        int* __restrict__ rowptr, int* __restrict__ cursor,
        float* __restrict__ dinv, int N, int E) {
    int i = blockIdx.x * 256 + threadIdx.x;
    if (i < N) {
        int d = deg[i];
        int start = bsum[blockIdx.x] + incl[i] - d;
        rowptr[i] = start;
        cursor[i] = start;
        dinv[i] = 1.0f / sqrtf((float)(d + 1));
    }
    if (i == N) rowptr[N] = E;
}

__global__ void fill_kernel(const int* __restrict__ src, const int* __restrict__ dst,
        int* __restrict__ cursor, int* __restrict__ colsrc, int E) {
    int e = blockIdx.x * blockDim.x + threadIdx.x;
    if (e < E) {
        int slot = atomicAdd(&cursor[dst[e]], 1);
        colsrc[slot] = src[e];
    }
}

// ---------------------------------------------------------------- weight split
// Produce Bt_hi/Bt_lo [n][k] bf16 planes (transposed W) for 8 weight matrices.
struct WPtrs { const float* w[8]; };

__global__ __launch_bounds__(256) void convw_kernel(WPtrs wp,
        unsigned short* __restrict__ bth, unsigned short* __restrict__ btl) {
    __shared__ unsigned short SH[64][72];
    __shared__ unsigned short SL[64][72];
    int mat = blockIdx.y;
    int tk = blockIdx.x >> 2, tn = blockIdx.x & 3;  // 64x64 tile coords
    const float* W = wp.w[mat];
    int kr = threadIdx.x >> 2, nc = (threadIdx.x & 3) * 16;
    const float* p = W + (size_t)(tk * 64 + kr) * 256 + tn * 64 + nc;
#pragma unroll
    for (int i = 0; i < 16; i++) {
        float v = p[i];
        unsigned short h = bftrunc(v);
        unsigned short l = bftrunc(v - bf2f(h));
        SH[nc + i][kr] = h;
        SL[nc + i][kr] = l;
    }
    __syncthreads();
    int nr = threadIdx.x >> 2, kc = (threadIdx.x & 3) * 16;
    size_t ob = (size_t)mat * 65536 + (size_t)(tn * 64 + nr) * 256 + tk * 64 + kc;
#pragma unroll
    for (int i = 0; i < 16; i++) {
        bth[ob + i] = SH[nr][kc + i];
        btl[ob + i] = SL[nr][kc + i];
    }
}

// ---------------------------------------------------------------- GEMM (split-bf16 MFMA)
// C[M,256] = act(A[M,256] @ W[256,256] + bias), W as transposed bf16 hi/lo planes.
// BM=128, BN=256, BK=32, 512 threads (8 waves, 4x2 wave grid, 32x128 per wave).
#define LDA 40  // bf16 elems per LDS row (32 + 8 pad), 80B stride

template<int ACT, int OBF16>
__global__ __launch_bounds__(512, 2) void gemm_mfma_kernel(
        const float* __restrict__ A,
        const unsigned short* __restrict__ BtH, const unsigned short* __restrict__ BtL,
        const float* __restrict__ bias, void* __restrict__ Cv, int M) {
    __shared__ unsigned short AsH[128 * LDA];
    __shared__ unsigned short AsL[128 * LDA];
    const int tid = threadIdx.x;
    const int row0 = blockIdx.x * 128;
    const int wave = tid >> 6, lane = tid & 63;
    const int wm = wave >> 1, wn = wave & 1;        // wave tile 32 rows x 128 cols
    const int lr = lane & 15, lk = (lane >> 4) * 8;
    const int srow = tid >> 2, skc = (tid & 3) * 8; // staging: 4 thr/row, 8 elems each
    const int arow = row0 + srow;
    const bool aok = arow < M;
    const float* aptr = A + (size_t)arow * 256 + skc;

    f32x4 acc[2][8];
#pragma unroll
    for (int m = 0; m < 2; m++)
#pragma unroll
        for (int n = 0; n < 8; n++) acc[m][n] = (f32x4)0.0f;

    float v[8];
    if (aok) {
        *(f32x4*)&v[0] = *(const f32x4*)(aptr);
        *(f32x4*)&v[4] = *(const f32x4*)(aptr + 4);
    } else {
#pragma unroll
        for (int i = 0; i < 8; i++) v[i] = 0.0f;
    }

    for (int k0 = 0; k0 < 256; k0 += 32) {
        // ---- split current k-tile into hi/lo bf16, store to LDS
        bf16x8 h, l;
#pragma unroll
        for (int i = 0; i < 8; i++) {
            unsigned short hh = bftrunc(v[i]);
            h[i] = (short)hh;
            l[i] = (short)bftrunc(v[i] - bf2f(hh));
        }
        *(bf16x8*)&AsH[srow * LDA + skc] = h;
        *(bf16x8*)&AsL[srow * LDA + skc] = l;
        __syncthreads();

        // ---- prefetch next A k-tile (hidden under MFMA)
        float vn[8];
        if (k0 < 224) {
            if (aok) {
                *(f32x4*)&vn[0] = *(const f32x4*)(aptr + k0 + 32);
                *(f32x4*)&vn[4] = *(const f32x4*)(aptr + k0 + 36);
            } else {
#pragma unroll
                for (int i = 0; i < 8; i++) vn[i] = 0.0f;
            }
        }

        // ---- B fragments from L2-resident transposed planes
        bf16x8 bh[8], bl[8];
#pragma unroll
        for (int n = 0; n < 8; n++) {
            size_t boff = (size_t)(wn * 128 + n * 16 + lr) * 256 + k0 + lk;
            bh[n] = *(const bf16x8*)&BtH[boff];
            bl[n] = *(const bf16x8*)&BtL[boff];
        }
        // ---- A fragments from LDS
        bf16x8 ah[2], al[2];
#pragma unroll
        for (int m = 0; m < 2; m++) {
            int r = (wm * 32 + m * 16 + lr) * LDA + lk;
            ah[m] = *(const bf16x8*)&AsH[r];
            al[m] = *(const bf16x8*)&AsL[r];
        }
#pragma unroll
        for (int m = 0; m < 2; m++)
#pragma unroll
            for (int n = 0; n < 8; n++) {
                acc[m][n] = __builtin_amdgcn_mfma_f32_16x16x32_bf16(ah[m], bh[n], acc[m][n], 0, 0, 0);
                acc[m][n] = __builtin_amdgcn_mfma_f32_16x16x32_bf16(ah[m], bl[n], acc[m][n], 0, 0, 0);
                acc[m][n] = __builtin_amdgcn_mfma_f32_16x16x32_bf16(al[m], bh[n], acc[m][n], 0, 0, 0);
            }
        __syncthreads();
        if (k0 < 224) {
#pragma unroll
            for (int i = 0; i < 8; i++) v[i] = vn[i];
        }
    }

    // ---- epilogue: C/D layout col=lane&15, row=(lane>>4)*4+j (m89-verified)
#pragma unroll
    for (int m = 0; m < 2; m++) {
        int rb = row0 + wm * 32 + m * 16 + (lane >> 4) * 4;
#pragma unroll
        for (int n = 0; n < 8; n++) {
            int col = wn * 128 + n * 16 + lr;
            float bv = bias ? bias[col] : 0.0f;
#pragma unroll
            for (int j = 0; j < 4; j++) {
                int r = rb + j;
                if (r < M) {
                    float x = acc[m][n][j] + bv;
                    if (ACT) x = x > 0.0f ? x : expm1f(x);
                    if (OBF16)
                        ((unsigned short*)Cv)[(size_t)r * 256 + col] = bfrtne(x);
                    else
                        ((float*)Cv)[(size_t)r * 256 + col] = x;
                }
            }
        }
    }
}

// ---------------------------------------------------------------- aggregation
// h is bf16 [N,256]. out fp32. 128 threads/node, 2 features/thread (bf16x2 loads).
__global__ __launch_bounds__(128) void agg_kernel(const unsigned short* __restrict__ h,
        const float* __restrict__ dinv, const int* __restrict__ rowptr,
        const int* __restrict__ colsrc, const float* __restrict__ bias,
        float* __restrict__ out, int doLN, const float* __restrict__ g,
        const float* __restrict__ lb) {
    __shared__ int sidx[64];
    __shared__ float sw[64];
    __shared__ float red[2];
    int node = blockIdx.x;
    int t = threadIdx.x;
    float di = dinv[node];
    unsigned u0 = ((const unsigned*)(h + (size_t)node * 256))[t];
    float acc0 = bf2f((unsigned short)u0) * di * di;
    float acc1 = bf2f((unsigned short)(u0 >> 16)) * di * di;
    int s0 = rowptr[node], s1 = rowptr[node + 1];
    for (int base = s0; base < s1; base += 64) {
        int cnt = min(64, s1 - base);
        if (t < cnt) {
            int s = colsrc[base + t];
            sidx[t] = s;
            sw[t] = dinv[s] * di;
        }
        __syncthreads();
        for (int i = 0; i < cnt; i++) {
            unsigned uu = ((const unsigned*)(h + (size_t)sidx[i] * 256))[t];
            float w = sw[i];
            acc0 = fmaf(bf2f((unsigned short)uu), w, acc0);
            acc1 = fmaf(bf2f((unsigned short)(uu >> 16)), w, acc1);
        }
        __syncthreads();
    }
    int j0 = t * 2;
    acc0 += bias[j0];
    acc1 += bias[j0 + 1];
    acc0 = acc0 > 0.0f ? acc0 : expm1f(acc0);
    acc1 = acc1 > 0.0f ? acc1 : expm1f(acc1);
    if (doLN) {
        int wid = t >> 6, lane = t & 63;
        float v = acc0 + acc1;
#pragma unroll
        for (int off = 32; off; off >>= 1) v += __shfl_down(v, off, 64);
        if (lane == 0) red[wid] = v;
        __syncthreads();
        float mu = (red[0] + red[1]) * (1.0f / 256.0f);
        __syncthreads();
        float d0 = acc0 - mu, d1 = acc1 - mu;
        v = d0 * d0 + d1 * d1;
#pragma unroll
        for (int off = 32; off; off >>= 1) v += __shfl_down(v, off, 64);
        if (lane == 0) red[wid] = v;
        __syncthreads();
        float var = (red[0] + red[1]) * (1.0f / 256.0f);
        float rs = rsqrtf(var + 1e-5f);
        acc0 = d0 * rs * g[j0] + lb[j0];
        acc1 = d1 * rs * g[j0 + 1] + lb[j0 + 1];
    }
    *(float2*)&out[(size_t)node * 256 + j0] = make_float2(acc0, acc1);
}

// ---------------------------------------------------------------- final head
__global__ __launch_bounds__(256) void final_kernel(const float* __restrict__ x,
        const float* __restrict__ W, const float* __restrict__ b,
        float* __restrict__ out, int M) {
    __shared__ float sW[256 * 25];
    for (int i = threadIdx.x; i < 256 * 25; i += 256) sW[i] = W[i];
    __syncthreads();
    int group = threadIdx.x >> 5;  // 8 nodes per block
    int c = threadIdx.x & 31;
    int node = blockIdx.x * 8 + group;
    if (node >= M || c >= 25) return;
    const float4* xr = (const float4*)(x + (size_t)node * 256);
    float acc = b[c];
#pragma unroll 8
    for (int k4 = 0; k4 < 64; k4++) {
        float4 xv = xr[k4];
        int k = k4 * 4;
        acc = fmaf(xv.x, sW[(k + 0) * 25 + c],
              fmaf(xv.y, sW[(k + 1) * 25 + c],
              fmaf(xv.z, sW[(k + 2) * 25 + c],
              fmaf(xv.w, sW[(k + 3) * 25 + c], acc))));
    }
    out[(size_t)node * 25 + c] = 1.0f / (1.0f + expf(-acc));
}

// ---------------------------------------------------------------- launch

extern "C" void kernel_launch(void* const* d_in, const int* in_sizes, int n_in,
                              void* d_out, int out_size, void* d_ws, size_t ws_size,
                              hipStream_t stream) {
    const float* x       = (const float*)d_in[0];
    const int*   ei      = (const int*)d_in[1];
    const float* W_mlp   = (const float*)d_in[2];
    const float* b_mlp   = (const float*)d_in[3];
    const float* W_conv1 = (const float*)d_in[4];
    const float* b_conv1 = (const float*)d_in[5];
    const float* W_hid   = (const float*)d_in[6];
    const float* b_hid   = (const float*)d_in[7];
    const float* ln_g    = (const float*)d_in[8];
    const float* ln_b    = (const float*)d_in[9];
    const float* W_post  = (const float*)d_in[10];
    const float* b_post  = (const float*)d_in[11];
    const float* W_lin   = (const float*)d_in[12];
    const float* b_lin   = (const float*)d_in[13];
    float* out = (float*)d_out;

    const int N = in_sizes[0] / HID;   // 50000
    const int E = in_sizes[1] / 2;     // 800000
    const int* src = ei;
    const int* dst = ei + E;
    const int NB = (N + 255) / 256;    // scan blocks (196)

    // workspace layout
    float* buf0   = (float*)d_ws;                   // N*256 fp32
    float* buf1   = buf0 + (size_t)N * HID;         // N*256 fp32 (bf16-aliased for conv h)
    float* dinv   = buf1 + (size_t)N * HID;         // N
    int*   deg    = (int*)(dinv + N);               // N
    int*   rowptr = deg + N;                        // N+1
    int*   cursor = rowptr + N + 1;                 // N
    int*   colsrc = cursor + N;                     // E
    int*   incl   = colsrc + E;                     // N
    int*   bsum   = incl + N;                       // NB (<=256)
    unsigned short* bth = (unsigned short*)(bsum + 256);  // 8*65536 bf16
    unsigned short* btl = bth + 8 * 65536;                // 8*65536 bf16
    unsigned short* hbf1 = (unsigned short*)buf1;         // bf16 view of buf1

    // ---- weight split (8 matrices -> transposed hi/lo bf16 planes)
    WPtrs wp;
    wp.w[0] = W_mlp;
    wp.w[1] = W_mlp + 65536;
    wp.w[2] = W_conv1;
    wp.w[3] = W_hid;
    wp.w[4] = W_hid + 65536;
    wp.w[5] = W_hid + 2 * 65536;
    wp.w[6] = W_post;
    wp.w[7] = W_post + 65536;
    convw_kernel<<<dim3(16, 8), 256, 0, stream>>>(wp, bth, btl);

    // ---- edge prep
    hipMemsetAsync(deg, 0, (size_t)N * sizeof(int), stream);
    hist_kernel<<<(E + 255) / 256, 256, 0, stream>>>(dst, deg, E);
    scan1_kernel<<<NB, 256, 0, stream>>>(deg, incl, bsum, N);
    scan2_kernel<<<1, 256, 0, stream>>>(bsum, NB);
    scan3_kernel<<<NB + 1, 256, 0, stream>>>(deg, incl, bsum, rowptr, cursor, dinv, N, E);
    fill_kernel<<<(E + 255) / 256, 256, 0, stream>>>(src, dst, cursor, colsrc, E);

    dim3 gg((N + 127) / 128);
    const size_t WM = 65536;

    // ---- pre-MLP (2 layers, fused celu, fp32): x -> buf1 -> buf0
    gemm_mfma_kernel<1, 0><<<gg, 512, 0, stream>>>(x,    bth + 0 * WM, btl + 0 * WM, b_mlp,       buf1, N);
    gemm_mfma_kernel<1, 0><<<gg, 512, 0, stream>>>(buf1, bth + 1 * WM, btl + 1 * WM, b_mlp + 256, buf0, N);

    // ---- conv1: h = buf0@Wc (bf16 into buf1), agg -> buf0 (celu, no LN)
    gemm_mfma_kernel<0, 1><<<gg, 512, 0, stream>>>(buf0, bth + 2 * WM, btl + 2 * WM, nullptr, buf1, N);
    agg_kernel<<<N, 128, 0, stream>>>(hbf1, dinv, rowptr, colsrc, b_conv1, buf0, 0, nullptr, nullptr);

    // ---- hidden convs (celu + layernorm): buf0 -> bf16(buf1) -> buf0
    for (int i = 0; i < 3; i++) {
        gemm_mfma_kernel<0, 1><<<gg, 512, 0, stream>>>(buf0, bth + (size_t)(3 + i) * WM, btl + (size_t)(3 + i) * WM, nullptr, buf1, N);
        agg_kernel<<<N, 128, 0, stream>>>(hbf1, dinv, rowptr, colsrc, b_hid + i * 256, buf0, 1, ln_g, ln_b);
    }

    // ---- post-MLP (2 layers, fused celu, fp32): buf0 -> buf1 -> buf0
    gemm_mfma_kernel<1, 0><<<gg, 512, 0, stream>>>(buf0, bth + 6 * WM, btl + 6 * WM, b_post,       buf1, N);
    gemm_mfma_kernel<1, 0><<<gg, 512, 0, stream>>>(buf1, bth + 7 * WM, btl + 7 * WM, b_post + 256, buf0, N);

    // ---- head + sigmoid
    final_kernel<<<(N + 7) / 8, 256, 0, stream>>>(buf0, W_lin, b_lin, out, N);
    (void)ws_size; (void)n_in; (void)out_size;
}

// Round 4
// 954.408 us; speedup vs baseline: 1.3670x; 1.3670x over previous
//
#include <hip/hip_runtime.h>
#include <hip/hip_bf16.h>
#include <math.h>

#define HID 256

typedef __attribute__((ext_vector_type(4))) float f32x4;
typedef __attribute__((ext_vector_type(8))) _Float16 f16x8;

static __device__ __forceinline__ unsigned short bfrtne(float v) {
    unsigned u = __float_as_uint(v);
    unsigned r = u + 0x7FFFu + ((u >> 16) & 1u);
    return (unsigned short)(r >> 16);
}
static __device__ __forceinline__ float bf2f(unsigned short s) {
    return __uint_as_float(((unsigned)s) << 16);
}

// ---------------------------------------------------------------- edge prep

__global__ void hist_kernel(const int* __restrict__ dst, int* __restrict__ deg, int E) {
    int e = blockIdx.x * blockDim.x + threadIdx.x;
    if (e < E) atomicAdd(&deg[dst[e]], 1);
}

__global__ __launch_bounds__(256) void scan1_kernel(const int* __restrict__ deg,
        int* __restrict__ incl, int* __restrict__ bsum, int N) {
    __shared__ int s[256];
    int i = blockIdx.x * 256 + threadIdx.x;
    int v = (i < N) ? deg[i] : 0;
    s[threadIdx.x] = v;
    __syncthreads();
#pragma unroll
    for (int off = 1; off < 256; off <<= 1) {
        int t = (threadIdx.x >= off) ? s[threadIdx.x - off] : 0;
        __syncthreads();
        s[threadIdx.x] += t;
        __syncthreads();
    }
    if (i < N) incl[i] = s[threadIdx.x];
    if (threadIdx.x == 255) bsum[blockIdx.x] = s[255];
}

__global__ __launch_bounds__(256) void scan2_kernel(int* __restrict__ bsum, int nb) {
    __shared__ int s[256];
    int v = (threadIdx.x < nb) ? bsum[threadIdx.x] : 0;
    s[threadIdx.x] = v;
    __syncthreads();
#pragma unroll
    for (int off = 1; off < 256; off <<= 1) {
        int t = (threadIdx.x >= off) ? s[threadIdx.x - off] : 0;
        __syncthreads();
        s[threadIdx.x] += t;
        __syncthreads();
    }
    if (threadIdx.x < nb) bsum[threadIdx.x] = s[threadIdx.x] - v;  // exclusive
}

__global__ __launch_bounds__(256) void scan3_kernel(const int* __restrict__ deg,
        const int* __restrict__ incl, const int* __restrict__ bsum,
        int* __restrict__ rowptr, int* __restrict__ cursor,
        float* __restrict__ dinv, int N, int E) {
    int i = blockIdx.x * 256 + threadIdx.x;
    if (i < N) {
        int d = deg[i];
        int start = bsum[blockIdx.x] + incl[i] - d;
        rowptr[i] = start;
        cursor[i] = start;
        dinv[i] = 1.0f / sqrtf((float)(d + 1));
    }
    if (i == N) rowptr[N] = E;
}

__global__ void fill_kernel(const int* __restrict__ src, const int* __restrict__ dst,
        int* __restrict__ cursor, int* __restrict__ colsrc, int E) {
    int e = blockIdx.x * blockDim.x + threadIdx.x;
    if (e < E) {
        int slot = atomicAdd(&cursor[dst[e]], 1);
        colsrc[slot] = src[e];
    }
}

// ---------------------------------------------------------------- weight prep
// Transposed f16 planes Bt[n][k] for the 8 hidden-dim weight matrices.
struct WPtrs { const float* w[8]; };

__global__ __launch_bounds__(256) void convw_kernel(WPtrs wp, _Float16* __restrict__ btf) {
    __shared__ _Float16 S[64][72];
    int mat = blockIdx.y;
    int tk = blockIdx.x >> 2, tn = blockIdx.x & 3;  // 64x64 tile
    const float* W = wp.w[mat];
    int kr = threadIdx.x >> 2, nc = (threadIdx.x & 3) * 16;
    const float* p = W + (size_t)(tk * 64 + kr) * 256 + tn * 64 + nc;
#pragma unroll
    for (int i = 0; i < 16; i++) S[nc + i][kr] = (_Float16)p[i];
    __syncthreads();
    int nr = threadIdx.x >> 2, kc = (threadIdx.x & 3) * 16;
    size_t ob = (size_t)mat * 65536 + (size_t)(tn * 64 + nr) * 256 + tk * 64 + kc;
#pragma unroll
    for (int i = 0; i < 16; i++) btf[ob + i] = S[nr][kc + i];
}

// ---------------------------------------------------------------- GEMM (f16 MFMA)
// C[M,256] = act(A[M,256] @ W[256,256] + bias); W as transposed f16 plane Bt[n][k].
// BM=128, BN=128, BK=32, 256 threads (4 waves as 2x2, 64x64 per wave).
#define LDA 40  // f16 elems per LDS row (32 + 8 pad), 80B stride, 16B-aligned

template<int ACT, int OBF16>
__global__ __launch_bounds__(256, 3) void gemm_mfma_kernel(
        const float* __restrict__ A, const _Float16* __restrict__ Bt,
        const float* __restrict__ bias, void* __restrict__ Cv, int M) {
    __shared__ _Float16 As[128 * LDA];
    const int tid = threadIdx.x;
    const int row0 = blockIdx.x * 128, col0 = blockIdx.y * 128;
    const int wave = tid >> 6, lane = tid & 63;
    const int wm = wave >> 1, wn = wave & 1;        // 64x64 wave tile
    const int lr = lane & 15, lk = (lane >> 4) * 8;
    const int srow = tid >> 1, skc = (tid & 1) * 16;  // 2 thr/row, 16 elems each
    const int arow = row0 + srow;
    const bool aok = arow < M;
    const float* aptr = A + (size_t)arow * 256 + skc;

    f32x4 acc[4][4];
#pragma unroll
    for (int m = 0; m < 4; m++)
#pragma unroll
        for (int n = 0; n < 4; n++) acc[m][n] = (f32x4)0.0f;

    float v[16];
    if (aok) {
#pragma unroll
        for (int q = 0; q < 4; q++) *(f32x4*)&v[q * 4] = *(const f32x4*)(aptr + q * 4);
    } else {
#pragma unroll
        for (int i = 0; i < 16; i++) v[i] = 0.0f;
    }

    for (int k0 = 0; k0 < 256; k0 += 32) {
        // ---- cvt current k-tile to f16, store to LDS
        f16x8 h0, h1;
#pragma unroll
        for (int i = 0; i < 8; i++) { h0[i] = (_Float16)v[i]; h1[i] = (_Float16)v[i + 8]; }
        *(f16x8*)&As[srow * LDA + skc] = h0;
        *(f16x8*)&As[srow * LDA + skc + 8] = h1;
        __syncthreads();

        // ---- prefetch next A k-tile into regs (hidden under MFMA)
        if (k0 < 224) {
            if (aok) {
#pragma unroll
                for (int q = 0; q < 4; q++) *(f32x4*)&v[q * 4] = *(const f32x4*)(aptr + k0 + 32 + q * 4);
            }
        }

        // ---- B fragments from L1/L2-resident transposed plane
        f16x8 bf[4];
#pragma unroll
        for (int n = 0; n < 4; n++)
            bf[n] = *(const f16x8*)&Bt[(size_t)(col0 + wn * 64 + n * 16 + lr) * 256 + k0 + lk];
        // ---- A fragments from LDS
        f16x8 af[4];
#pragma unroll
        for (int m = 0; m < 4; m++)
            af[m] = *(const f16x8*)&As[(wm * 64 + m * 16 + lr) * LDA + lk];
#pragma unroll
        for (int m = 0; m < 4; m++)
#pragma unroll
            for (int n = 0; n < 4; n++)
                acc[m][n] = __builtin_amdgcn_mfma_f32_16x16x32_f16(af[m], bf[n], acc[m][n], 0, 0, 0);
        __syncthreads();
    }

    // ---- epilogue: C/D layout col=lane&15, row=(lane>>4)*4+j (m89-verified)
#pragma unroll
    for (int m = 0; m < 4; m++) {
        int rb = row0 + wm * 64 + m * 16 + (lane >> 4) * 4;
#pragma unroll
        for (int n = 0; n < 4; n++) {
            int col = col0 + wn * 64 + n * 16 + lr;
            float bv = bias ? bias[col] : 0.0f;
#pragma unroll
            for (int j = 0; j < 4; j++) {
                int r = rb + j;
                if (r < M) {
                    float x = acc[m][n][j] + bv;
                    if (ACT) x = x > 0.0f ? x : expm1f(x);
                    if (OBF16)
                        ((unsigned short*)Cv)[(size_t)r * 256 + col] = bfrtne(x);
                    else
                        ((float*)Cv)[(size_t)r * 256 + col] = x;
                }
            }
        }
    }
}

// ---------------------------------------------------------------- aggregation
// h bf16 [N,256]; out fp32. 128 threads/node, 2 features/thread.
__global__ __launch_bounds__(128) void agg_kernel(const unsigned short* __restrict__ h,
        const float* __restrict__ dinv, const int* __restrict__ rowptr,
        const int* __restrict__ colsrc, const float* __restrict__ bias,
        float* __restrict__ out, int doLN, const float* __restrict__ g,
        const float* __restrict__ lb) {
    __shared__ int sidx[64];
    __shared__ float sw[64];
    __shared__ float red[2];
    int node = blockIdx.x;
    int t = threadIdx.x;
    float di = dinv[node];
    unsigned u0 = ((const unsigned*)(h + (size_t)node * 256))[t];
    float acc0 = bf2f((unsigned short)u0) * di * di;
    float acc1 = bf2f((unsigned short)(u0 >> 16)) * di * di;
    int s0 = rowptr[node], s1 = rowptr[node + 1];
    for (int base = s0; base < s1; base += 64) {
        int cnt = min(64, s1 - base);
        if (t < cnt) {
            int s = colsrc[base + t];
            sidx[t] = s;
            sw[t] = dinv[s] * di;
        }
        __syncthreads();
        for (int i = 0; i < cnt; i++) {
            unsigned uu = ((const unsigned*)(h + (size_t)sidx[i] * 256))[t];
            float w = sw[i];
            acc0 = fmaf(bf2f((unsigned short)uu), w, acc0);
            acc1 = fmaf(bf2f((unsigned short)(uu >> 16)), w, acc1);
        }
        __syncthreads();
    }
    int j0 = t * 2;
    acc0 += bias[j0];
    acc1 += bias[j0 + 1];
    acc0 = acc0 > 0.0f ? acc0 : expm1f(acc0);
    acc1 = acc1 > 0.0f ? acc1 : expm1f(acc1);
    if (doLN) {
        int wid = t >> 6, lane = t & 63;
        float v = acc0 + acc1;
#pragma unroll
        for (int off = 32; off; off >>= 1) v += __shfl_down(v, off, 64);
        if (lane == 0) red[wid] = v;
        __syncthreads();
        float mu = (red[0] + red[1]) * (1.0f / 256.0f);
        __syncthreads();
        float d0 = acc0 - mu, d1 = acc1 - mu;
        v = d0 * d0 + d1 * d1;
#pragma unroll
        for (int off = 32; off; off >>= 1) v += __shfl_down(v, off, 64);
        if (lane == 0) red[wid] = v;
        __syncthreads();
        float var = (red[0] + red[1]) * (1.0f / 256.0f);
        float rs = rsqrtf(var + 1e-5f);
        acc0 = d0 * rs * g[j0] + lb[j0];
        acc1 = d1 * rs * g[j0 + 1] + lb[j0 + 1];
    }
    *(float2*)&out[(size_t)node * 256 + j0] = make_float2(acc0, acc1);
}

// ---------------------------------------------------------------- final head
__global__ __launch_bounds__(256) void final_kernel(const float* __restrict__ x,
        const float* __restrict__ W, const float* __restrict__ b,
        float* __restrict__ out, int M) {
    __shared__ float sW[256 * 25];
    for (int i = threadIdx.x; i < 256 * 25; i += 256) sW[i] = W[i];
    __syncthreads();
    int group = threadIdx.x >> 5;  // 8 nodes per block
    int c = threadIdx.x & 31;
    int node = blockIdx.x * 8 + group;
    if (node >= M || c >= 25) return;
    const float4* xr = (const float4*)(x + (size_t)node * 256);
    float acc = b[c];
#pragma unroll 8
    for (int k4 = 0; k4 < 64; k4++) {
        float4 xv = xr[k4];
        int k = k4 * 4;
        acc = fmaf(xv.x, sW[(k + 0) * 25 + c],
              fmaf(xv.y, sW[(k + 1) * 25 + c],
              fmaf(xv.z, sW[(k + 2) * 25 + c],
              fmaf(xv.w, sW[(k + 3) * 25 + c], acc))));
    }
    out[(size_t)node * 25 + c] = 1.0f / (1.0f + expf(-acc));
}

// ---------------------------------------------------------------- launch

extern "C" void kernel_launch(void* const* d_in, const int* in_sizes, int n_in,
                              void* d_out, int out_size, void* d_ws, size_t ws_size,
                              hipStream_t stream) {
    const float* x       = (const float*)d_in[0];
    const int*   ei      = (const int*)d_in[1];
    const float* W_mlp   = (const float*)d_in[2];
    const float* b_mlp   = (const float*)d_in[3];
    const float* W_conv1 = (const float*)d_in[4];
    const float* b_conv1 = (const float*)d_in[5];
    const float* W_hid   = (const float*)d_in[6];
    const float* b_hid   = (const float*)d_in[7];
    const float* ln_g    = (const float*)d_in[8];
    const float* ln_b    = (const float*)d_in[9];
    const float* W_post  = (const float*)d_in[10];
    const float* b_post  = (const float*)d_in[11];
    const float* W_lin   = (const float*)d_in[12];
    const float* b_lin   = (const float*)d_in[13];
    float* out = (float*)d_out;

    const int N = in_sizes[0] / HID;   // 50000
    const int E = in_sizes[1] / 2;     // 800000
    const int* src = ei;
    const int* dst = ei + E;
    const int NB = (N + 255) / 256;

    // workspace layout
    float* buf0   = (float*)d_ws;                   // N*256 fp32
    float* buf1   = buf0 + (size_t)N * HID;         // N*256 fp32 (bf16-aliased for conv h)
    float* dinv   = buf1 + (size_t)N * HID;         // N
    int*   deg    = (int*)(dinv + N);               // N
    int*   rowptr = deg + N;                        // N+1
    int*   cursor = rowptr + N + 1;                 // N
    int*   colsrc = cursor + N;                     // E
    int*   incl   = colsrc + E;                     // N
    int*   bsum   = incl + N;                       // <=256
    _Float16* btf = (_Float16*)(bsum + 256);        // 8*65536 f16
    unsigned short* hbf1 = (unsigned short*)buf1;

    // ---- weight prep (8 matrices -> transposed f16 planes)
    WPtrs wp;
    wp.w[0] = W_mlp;
    wp.w[1] = W_mlp + 65536;
    wp.w[2] = W_conv1;
    wp.w[3] = W_hid;
    wp.w[4] = W_hid + 65536;
    wp.w[5] = W_hid + 2 * 65536;
    wp.w[6] = W_post;
    wp.w[7] = W_post + 65536;
    convw_kernel<<<dim3(16, 8), 256, 0, stream>>>(wp, btf);

    // ---- edge prep
    hipMemsetAsync(deg, 0, (size_t)N * sizeof(int), stream);
    hist_kernel<<<(E + 255) / 256, 256, 0, stream>>>(dst, deg, E);
    scan1_kernel<<<NB, 256, 0, stream>>>(deg, incl, bsum, N);
    scan2_kernel<<<1, 256, 0, stream>>>(bsum, NB);
    scan3_kernel<<<NB + 1, 256, 0, stream>>>(deg, incl, bsum, rowptr, cursor, dinv, N, E);
    fill_kernel<<<(E + 255) / 256, 256, 0, stream>>>(src, dst, cursor, colsrc, E);

    dim3 gg((N + 127) / 128, 2);
    const size_t WM = 65536;

    // ---- pre-MLP: x -> buf1 -> buf0 (celu, fp32)
    gemm_mfma_kernel<1, 0><<<gg, 256, 0, stream>>>(x,    btf + 0 * WM, b_mlp,       buf1, N);
    gemm_mfma_kernel<1, 0><<<gg, 256, 0, stream>>>(buf1, btf + 1 * WM, b_mlp + 256, buf0, N);

    // ---- conv1: h = buf0@Wc (bf16 -> buf1), agg -> buf0 (celu, no LN)
    gemm_mfma_kernel<0, 1><<<gg, 256, 0, stream>>>(buf0, btf + 2 * WM, nullptr, buf1, N);
    agg_kernel<<<N, 128, 0, stream>>>(hbf1, dinv, rowptr, colsrc, b_conv1, buf0, 0, nullptr, nullptr);

    // ---- hidden convs: buf0 -> bf16(buf1) -> buf0 (celu + LN)
    for (int i = 0; i < 3; i++) {
        gemm_mfma_kernel<0, 1><<<gg, 256, 0, stream>>>(buf0, btf + (size_t)(3 + i) * WM, nullptr, buf1, N);
        agg_kernel<<<N, 128, 0, stream>>>(hbf1, dinv, rowptr, colsrc, b_hid + i * 256, buf0, 1, ln_g, ln_b);
    }

    // ---- post-MLP: buf0 -> buf1 -> buf0 (celu, fp32)
    gemm_mfma_kernel<1, 0><<<gg, 256, 0, stream>>>(buf0, btf + 6 * WM, b_post,       buf1, N);
    gemm_mfma_kernel<1, 0><<<gg, 256, 0, stream>>>(buf1, btf + 7 * WM, b_post + 256, buf0, N);

    // ---- head + sigmoid
    final_kernel<<<(N + 7) / 8, 256, 0, stream>>>(buf0, W_lin, b_lin, out, N);
    (void)ws_size; (void)n_in; (void)out_size;
}

// Round 5
// 860.478 us; speedup vs baseline: 1.5162x; 1.1092x over previous
//
#include <hip/hip_runtime.h>
#include <hip/hip_bf16.h>
#include <math.h>

#define HID 256

typedef __attribute__((ext_vector_type(4))) float f32x4;
typedef __attribute__((ext_vector_type(8))) _Float16 f16x8;

static __device__ __forceinline__ float f16tof(unsigned short u) {
    _Float16 h; __builtin_memcpy(&h, &u, 2); return (float)h;
}
static __device__ __forceinline__ unsigned short ftof16(float f) {
    _Float16 h = (_Float16)f; unsigned short u; __builtin_memcpy(&u, &h, 2); return u;
}

// ---------------------------------------------------------------- edge prep

__global__ void hist_kernel(const int* __restrict__ dst, int* __restrict__ deg, int E) {
    int e = blockIdx.x * blockDim.x + threadIdx.x;
    if (e < E) atomicAdd(&deg[dst[e]], 1);
}

__global__ __launch_bounds__(256) void scan1_kernel(const int* __restrict__ deg,
        int* __restrict__ incl, int* __restrict__ bsum, int N) {
    __shared__ int s[256];
    int i = blockIdx.x * 256 + threadIdx.x;
    int v = (i < N) ? deg[i] : 0;
    s[threadIdx.x] = v;
    __syncthreads();
#pragma unroll
    for (int off = 1; off < 256; off <<= 1) {
        int t = (threadIdx.x >= off) ? s[threadIdx.x - off] : 0;
        __syncthreads();
        s[threadIdx.x] += t;
        __syncthreads();
    }
    if (i < N) incl[i] = s[threadIdx.x];
    if (threadIdx.x == 255) bsum[blockIdx.x] = s[255];
}

__global__ __launch_bounds__(256) void scan2_kernel(int* __restrict__ bsum, int nb) {
    __shared__ int s[256];
    int v = (threadIdx.x < nb) ? bsum[threadIdx.x] : 0;
    s[threadIdx.x] = v;
    __syncthreads();
#pragma unroll
    for (int off = 1; off < 256; off <<= 1) {
        int t = (threadIdx.x >= off) ? s[threadIdx.x - off] : 0;
        __syncthreads();
        s[threadIdx.x] += t;
        __syncthreads();
    }
    if (threadIdx.x < nb) bsum[threadIdx.x] = s[threadIdx.x] - v;  // exclusive
}

__global__ __launch_bounds__(256) void scan3_kernel(const int* __restrict__ deg,
        const int* __restrict__ incl, const int* __restrict__ bsum,
        int* __restrict__ rowptr, int* __restrict__ cursor,
        float* __restrict__ dinv, int N, int E) {
    int i = blockIdx.x * 256 + threadIdx.x;
    if (i < N) {
        int d = deg[i];
        int start = bsum[blockIdx.x] + incl[i] - d;
        rowptr[i] = start;
        cursor[i] = start;
        dinv[i] = 1.0f / sqrtf((float)(d + 1));
    }
    if (i == N) rowptr[N] = E;
}

__global__ void fill_kernel(const int* __restrict__ src, const int* __restrict__ dst,
        int* __restrict__ cursor, int* __restrict__ colsrc, int E) {
    int e = blockIdx.x * blockDim.x + threadIdx.x;
    if (e < E) {
        int slot = atomicAdd(&cursor[dst[e]], 1);
        colsrc[slot] = src[e];
    }
}

// ---------------------------------------------------------------- weight prep
// Transposed f16 planes Bt[n][k] for the 8 hidden-dim weight matrices.
struct WPtrs { const float* w[8]; };

__global__ __launch_bounds__(256) void convw_kernel(WPtrs wp, _Float16* __restrict__ btf) {
    __shared__ _Float16 S[64][72];
    int mat = blockIdx.y;
    int tk = blockIdx.x >> 2, tn = blockIdx.x & 3;  // 64x64 tile
    const float* W = wp.w[mat];
    int kr = threadIdx.x >> 2, nc = (threadIdx.x & 3) * 16;
    const float* p = W + (size_t)(tk * 64 + kr) * 256 + tn * 64 + nc;
#pragma unroll
    for (int i = 0; i < 16; i++) S[nc + i][kr] = (_Float16)p[i];
    __syncthreads();
    int nr = threadIdx.x >> 2, kc = (threadIdx.x & 3) * 16;
    size_t ob = (size_t)mat * 65536 + (size_t)(tn * 64 + nr) * 256 + tk * 64 + kc;
#pragma unroll
    for (int i = 0; i < 16; i++) btf[ob + i] = S[nr][kc + i];
}

// ---------------------------------------------------------------- GEMM (f16 MFMA)
// C[M,256](f16) = act(A[M,256] @ W[256,256] + bias); Bt[n][k] f16 transposed plane.
// BM=64, BN=128, 128 threads (2 waves side-by-side in N; each wave 64x64).
// A tile (64x256) staged to LDS ONCE (XOR-swizzled), then barrier-free K-loop.

template<int ACT, int INF32>
__global__ __launch_bounds__(128, 2) void gemm_kernel(
        const void* __restrict__ Av, const _Float16* __restrict__ Bt,
        const float* __restrict__ bias, unsigned short* __restrict__ C, int M) {
    __shared__ _Float16 As[64 * 256];  // 32 KB; row stride 512B; byte ^= ((row&7)<<4)
    const int tid = threadIdx.x;
    const int row0 = blockIdx.x * 64, col0 = blockIdx.y * 128;
    const int wn = tid >> 6, lane = tid & 63;
    const int lr = lane & 15, lk = (lane >> 4) * 8;

    // ---- stage A (64 rows x 256 k) as f16, swizzled; 2 threads/row
    {
        const int srow = tid >> 1, sh = tid & 1;
        const int grow = row0 + srow;
        char* db = (char*)As + srow * 512;
        const int sw = (srow & 7) << 4;
        if (INF32) {
            const float* ap = (const float*)Av + (size_t)grow * 256 + sh * 128;
            if (grow < M) {
#pragma unroll
                for (int c = 0; c < 16; c++) {
                    f32x4 v0 = *(const f32x4*)(ap + c * 8);
                    f32x4 v1 = *(const f32x4*)(ap + c * 8 + 4);
                    f16x8 hv;
#pragma unroll
                    for (int i = 0; i < 4; i++) { hv[i] = (_Float16)v0[i]; hv[i + 4] = (_Float16)v1[i]; }
                    *(f16x8*)(db + ((sh * 256 + c * 16) ^ sw)) = hv;
                }
            } else {
#pragma unroll
                for (int c = 0; c < 16; c++)
                    *(f16x8*)(db + ((sh * 256 + c * 16) ^ sw)) = (f16x8)(_Float16)0.0f;
            }
        } else {
            const _Float16* ap = (const _Float16*)Av + (size_t)grow * 256 + sh * 128;
            if (grow < M) {
#pragma unroll
                for (int c = 0; c < 16; c++)
                    *(f16x8*)(db + ((sh * 256 + c * 16) ^ sw)) = *(const f16x8*)(ap + c * 8);
            } else {
#pragma unroll
                for (int c = 0; c < 16; c++)
                    *(f16x8*)(db + ((sh * 256 + c * 16) ^ sw)) = (f16x8)(_Float16)0.0f;
            }
        }
    }
    __syncthreads();

    f32x4 acc[4][4];
#pragma unroll
    for (int m = 0; m < 4; m++)
#pragma unroll
        for (int n = 0; n < 4; n++) acc[m][n] = (f32x4)0.0f;

#pragma unroll 2
    for (int k0 = 0; k0 < 256; k0 += 32) {
        f16x8 bf[4], af[4];
#pragma unroll
        for (int n = 0; n < 4; n++)
            bf[n] = *(const f16x8*)&Bt[(size_t)(col0 + wn * 64 + n * 16 + lr) * 256 + k0 + lk];
#pragma unroll
        for (int m = 0; m < 4; m++) {
            int fr = m * 16 + lr;
            af[m] = *(const f16x8*)((char*)As + fr * 512 + ((k0 * 2 + (lane >> 4) * 16) ^ ((fr & 7) << 4)));
        }
#pragma unroll
        for (int m = 0; m < 4; m++)
#pragma unroll
            for (int n = 0; n < 4; n++)
                acc[m][n] = __builtin_amdgcn_mfma_f32_16x16x32_f16(af[m], bf[n], acc[m][n], 0, 0, 0);
    }

    // ---- epilogue: C/D layout col=lane&15, row=(lane>>4)*4+j
#pragma unroll
    for (int m = 0; m < 4; m++) {
        int rb = row0 + m * 16 + (lane >> 4) * 4;
#pragma unroll
        for (int n = 0; n < 4; n++) {
            int col = col0 + wn * 64 + n * 16 + lr;
            float bv = bias ? bias[col] : 0.0f;
#pragma unroll
            for (int j = 0; j < 4; j++) {
                int r = rb + j;
                if (r < M) {
                    float xv = acc[m][n][j] + bv;
                    if (ACT) xv = xv > 0.0f ? xv : expm1f(xv);
                    C[(size_t)r * 256 + col] = ftof16(xv);
                }
            }
        }
    }
}

// ---------------------------------------------------------------- aggregation
// h f16 [N,256]; out f16. 256 threads = 4 waves = 4 nodes; per-wave LDS staging,
// NO block barriers. Each lane: 4 feats via uint2 (8B) gathers.
__global__ __launch_bounds__(256) void agg_kernel(const unsigned short* __restrict__ h,
        const float* __restrict__ dinv, const int* __restrict__ rowptr,
        const int* __restrict__ colsrc, const float* __restrict__ bias,
        unsigned short* __restrict__ out, int doLN, const float* __restrict__ g,
        const float* __restrict__ lb, int N) {
    __shared__ int2 se[4][64];
    const int w = threadIdx.x >> 6, lane = threadIdx.x & 63;
    const int node = blockIdx.x * 4 + w;
    if (node >= N) return;
    const float di = dinv[node];
    const float dd = di * di;
    const int j0 = lane * 4;

    uint2 us = *(const uint2*)(h + (size_t)node * 256 + j0);
    float acc0 = f16tof((unsigned short)(us.x & 0xFFFF)) * dd;
    float acc1 = f16tof((unsigned short)(us.x >> 16)) * dd;
    float acc2 = f16tof((unsigned short)(us.y & 0xFFFF)) * dd;
    float acc3 = f16tof((unsigned short)(us.y >> 16)) * dd;

    const int s0 = rowptr[node], s1 = rowptr[node + 1];
    for (int base = s0; base < s1; base += 64) {
        int cnt = min(64, s1 - base);
        if (lane < cnt) {
            int s = colsrc[base + lane];
            se[w][lane] = make_int2(s, __float_as_int(dinv[s] * di));
        }
        // same-wave LDS write->read: ordered by lgkmcnt, no barrier needed
#pragma unroll 4
        for (int i = 0; i < cnt; i++) {
            int2 e = se[w][i];
            uint2 uu = *(const uint2*)(h + (size_t)e.x * 256 + j0);
            float wt = __int_as_float(e.y);
            acc0 = fmaf(f16tof((unsigned short)(uu.x & 0xFFFF)), wt, acc0);
            acc1 = fmaf(f16tof((unsigned short)(uu.x >> 16)), wt, acc1);
            acc2 = fmaf(f16tof((unsigned short)(uu.y & 0xFFFF)), wt, acc2);
            acc3 = fmaf(f16tof((unsigned short)(uu.y >> 16)), wt, acc3);
        }
    }

    f32x4 bv = *(const f32x4*)(bias + j0);
    acc0 += bv[0]; acc1 += bv[1]; acc2 += bv[2]; acc3 += bv[3];
    acc0 = acc0 > 0.0f ? acc0 : expm1f(acc0);
    acc1 = acc1 > 0.0f ? acc1 : expm1f(acc1);
    acc2 = acc2 > 0.0f ? acc2 : expm1f(acc2);
    acc3 = acc3 > 0.0f ? acc3 : expm1f(acc3);

    if (doLN) {
        float v = acc0 + acc1 + acc2 + acc3;
#pragma unroll
        for (int off = 32; off; off >>= 1) v += __shfl_xor(v, off, 64);
        float mu = v * (1.0f / 256.0f);
        float d0 = acc0 - mu, d1 = acc1 - mu, d2 = acc2 - mu, d3 = acc3 - mu;
        float q = d0 * d0 + d1 * d1 + d2 * d2 + d3 * d3;
#pragma unroll
        for (int off = 32; off; off >>= 1) q += __shfl_xor(q, off, 64);
        float rs = rsqrtf(q * (1.0f / 256.0f) + 1e-5f);
        f32x4 gv = *(const f32x4*)(g + j0);
        f32x4 lv = *(const f32x4*)(lb + j0);
        acc0 = d0 * rs * gv[0] + lv[0];
        acc1 = d1 * rs * gv[1] + lv[1];
        acc2 = d2 * rs * gv[2] + lv[2];
        acc3 = d3 * rs * gv[3] + lv[3];
    }

    unsigned lo = (unsigned)ftof16(acc0) | ((unsigned)ftof16(acc1) << 16);
    unsigned hi = (unsigned)ftof16(acc2) | ((unsigned)ftof16(acc3) << 16);
    *(uint2*)(out + (size_t)node * 256 + j0) = make_uint2(lo, hi);
}

// ---------------------------------------------------------------- final head
// out[M,25] = sigmoid(x[M,256](f16) @ W[256,25] + b)
__global__ __launch_bounds__(256) void final_kernel(const unsigned short* __restrict__ x,
        const float* __restrict__ W, const float* __restrict__ b,
        float* __restrict__ out, int M) {
    __shared__ float sW[256 * 25];
    for (int i = threadIdx.x; i < 256 * 25; i += 256) sW[i] = W[i];
    __syncthreads();
    int group = threadIdx.x >> 5;  // 8 nodes per block
    int c = threadIdx.x & 31;
    int node = blockIdx.x * 8 + group;
    if (node >= M || c >= 25) return;
    const uint2* xr = (const uint2*)(x + (size_t)node * 256);
    float acc = b[c];
#pragma unroll 8
    for (int k4 = 0; k4 < 64; k4++) {
        uint2 v = xr[k4];
        int k = k4 * 4;
        acc = fmaf(f16tof((unsigned short)(v.x & 0xFFFF)), sW[(k + 0) * 25 + c],
              fmaf(f16tof((unsigned short)(v.x >> 16)),   sW[(k + 1) * 25 + c],
              fmaf(f16tof((unsigned short)(v.y & 0xFFFF)), sW[(k + 2) * 25 + c],
              fmaf(f16tof((unsigned short)(v.y >> 16)),    sW[(k + 3) * 25 + c], acc))));
    }
    out[(size_t)node * 25 + c] = 1.0f / (1.0f + expf(-acc));
}

// ---------------------------------------------------------------- launch

extern "C" void kernel_launch(void* const* d_in, const int* in_sizes, int n_in,
                              void* d_out, int out_size, void* d_ws, size_t ws_size,
                              hipStream_t stream) {
    const float* x       = (const float*)d_in[0];
    const int*   ei      = (const int*)d_in[1];
    const float* W_mlp   = (const float*)d_in[2];
    const float* b_mlp   = (const float*)d_in[3];
    const float* W_conv1 = (const float*)d_in[4];
    const float* b_conv1 = (const float*)d_in[5];
    const float* W_hid   = (const float*)d_in[6];
    const float* b_hid   = (const float*)d_in[7];
    const float* ln_g    = (const float*)d_in[8];
    const float* ln_b    = (const float*)d_in[9];
    const float* W_post  = (const float*)d_in[10];
    const float* b_post  = (const float*)d_in[11];
    const float* W_lin   = (const float*)d_in[12];
    const float* b_lin   = (const float*)d_in[13];
    float* out = (float*)d_out;

    const int N = in_sizes[0] / HID;   // 50000
    const int E = in_sizes[1] / 2;     // 800000
    const int* src = ei;
    const int* dst = ei + E;
    const int NB = (N + 255) / 256;

    // workspace layout (f16 activations)
    unsigned short* buf0 = (unsigned short*)d_ws;          // N*256 f16
    unsigned short* buf1 = buf0 + (size_t)N * HID;         // N*256 f16
    float* dinv   = (float*)(buf1 + (size_t)N * HID);      // N
    int*   deg    = (int*)(dinv + N);                      // N
    int*   rowptr = deg + N;                               // N+1
    int*   cursor = rowptr + N + 1;                        // N
    int*   colsrc = cursor + N;                            // E
    int*   incl   = colsrc + E;                            // N
    int*   bsum   = incl + N;                              // <=256
    _Float16* btf = (_Float16*)(bsum + 256);               // 8*65536 f16

    // ---- weight prep (8 matrices -> transposed f16 planes)
    WPtrs wp;
    wp.w[0] = W_mlp;
    wp.w[1] = W_mlp + 65536;
    wp.w[2] = W_conv1;
    wp.w[3] = W_hid;
    wp.w[4] = W_hid + 65536;
    wp.w[5] = W_hid + 2 * 65536;
    wp.w[6] = W_post;
    wp.w[7] = W_post + 65536;
    convw_kernel<<<dim3(16, 8), 256, 0, stream>>>(wp, btf);

    // ---- edge prep
    hipMemsetAsync(deg, 0, (size_t)N * sizeof(int), stream);
    hist_kernel<<<(E + 255) / 256, 256, 0, stream>>>(dst, deg, E);
    scan1_kernel<<<NB, 256, 0, stream>>>(deg, incl, bsum, N);
    scan2_kernel<<<1, 256, 0, stream>>>(bsum, NB);
    scan3_kernel<<<NB + 1, 256, 0, stream>>>(deg, incl, bsum, rowptr, cursor, dinv, N, E);
    fill_kernel<<<(E + 255) / 256, 256, 0, stream>>>(src, dst, cursor, colsrc, E);

    dim3 gg((N + 63) / 64, 2);
    const size_t WM = 65536;

    // ---- pre-MLP: x(f32) -> buf1 -> buf0 (celu, f16)
    gemm_kernel<1, 1><<<gg, 128, 0, stream>>>(x,    btf + 0 * WM, b_mlp,       buf1, N);
    gemm_kernel<1, 0><<<gg, 128, 0, stream>>>(buf1, btf + 1 * WM, b_mlp + 256, buf0, N);

    // ---- conv1: h = buf0@Wc -> buf1 (f16), agg -> buf0 (celu, no LN)
    gemm_kernel<0, 0><<<gg, 128, 0, stream>>>(buf0, btf + 2 * WM, nullptr, buf1, N);
    agg_kernel<<<(N + 3) / 4, 256, 0, stream>>>(buf1, dinv, rowptr, colsrc, b_conv1, buf0, 0, nullptr, nullptr, N);

    // ---- hidden convs: buf0 -> buf1 -> buf0 (celu + LN)
    for (int i = 0; i < 3; i++) {
        gemm_kernel<0, 0><<<gg, 128, 0, stream>>>(buf0, btf + (size_t)(3 + i) * WM, nullptr, buf1, N);
        agg_kernel<<<(N + 3) / 4, 256, 0, stream>>>(buf1, dinv, rowptr, colsrc, b_hid + i * 256, buf0, 1, ln_g, ln_b, N);
    }

    // ---- post-MLP: buf0 -> buf1 -> buf0 (celu, f16)
    gemm_kernel<1, 0><<<gg, 128, 0, stream>>>(buf0, btf + 6 * WM, b_post,       buf1, N);
    gemm_kernel<1, 0><<<gg, 128, 0, stream>>>(buf1, btf + 7 * WM, b_post + 256, buf0, N);

    // ---- head + sigmoid
    final_kernel<<<(N + 7) / 8, 256, 0, stream>>>(buf0, W_lin, b_lin, out, N);
    (void)ws_size; (void)n_in; (void)out_size;
}

// Round 6
// 661.856 us; speedup vs baseline: 1.9712x; 1.3001x over previous
//
#include <hip/hip_runtime.h>
#include <hip/hip_bf16.h>
#include <math.h>

#define HID 256

typedef __attribute__((ext_vector_type(4))) float f32x4;
typedef __attribute__((ext_vector_type(8))) _Float16 f16x8;

static __device__ __forceinline__ float f16tof(unsigned short u) {
    _Float16 h; __builtin_memcpy(&h, &u, 2); return (float)h;
}
static __device__ __forceinline__ unsigned short ftof16(float f) {
    _Float16 h = (_Float16)f; unsigned short u; __builtin_memcpy(&u, &h, 2); return u;
}

// async global->LDS, 16B per lane (dest = wave-uniform base + lane*16)
static __device__ __forceinline__ void gld16(const void* g, void* l) {
    __builtin_amdgcn_global_load_lds(
        (const __attribute__((address_space(1))) void*)g,
        (__attribute__((address_space(3))) void*)l, 16, 0, 0);
}

// ---------------------------------------------------------------- edge prep

__global__ void hist_kernel(const int* __restrict__ dst, int* __restrict__ deg, int E) {
    int e = blockIdx.x * blockDim.x + threadIdx.x;
    if (e < E) atomicAdd(&deg[dst[e]], 1);
}

__global__ __launch_bounds__(256) void scan1_kernel(const int* __restrict__ deg,
        int* __restrict__ incl, int* __restrict__ bsum, int N) {
    __shared__ int s[256];
    int i = blockIdx.x * 256 + threadIdx.x;
    int v = (i < N) ? deg[i] : 0;
    s[threadIdx.x] = v;
    __syncthreads();
#pragma unroll
    for (int off = 1; off < 256; off <<= 1) {
        int t = (threadIdx.x >= off) ? s[threadIdx.x - off] : 0;
        __syncthreads();
        s[threadIdx.x] += t;
        __syncthreads();
    }
    if (i < N) incl[i] = s[threadIdx.x];
    if (threadIdx.x == 255) bsum[blockIdx.x] = s[255];
}

__global__ __launch_bounds__(256) void scan2_kernel(int* __restrict__ bsum, int nb) {
    __shared__ int s[256];
    int v = (threadIdx.x < nb) ? bsum[threadIdx.x] : 0;
    s[threadIdx.x] = v;
    __syncthreads();
#pragma unroll
    for (int off = 1; off < 256; off <<= 1) {
        int t = (threadIdx.x >= off) ? s[threadIdx.x - off] : 0;
        __syncthreads();
        s[threadIdx.x] += t;
        __syncthreads();
    }
    if (threadIdx.x < nb) bsum[threadIdx.x] = s[threadIdx.x] - v;  // exclusive
}

__global__ __launch_bounds__(256) void scan3_kernel(const int* __restrict__ deg,
        const int* __restrict__ incl, const int* __restrict__ bsum,
        int* __restrict__ rowptr, int* __restrict__ cursor,
        float* __restrict__ dinv, int N, int E) {
    int i = blockIdx.x * 256 + threadIdx.x;
    if (i < N) {
        int d = deg[i];
        int start = bsum[blockIdx.x] + incl[i] - d;
        rowptr[i] = start;
        cursor[i] = start;
        dinv[i] = 1.0f / sqrtf((float)(d + 1));
    }
    if (i == N) rowptr[N] = E;
}

__global__ void fill_kernel(const int* __restrict__ src, const int* __restrict__ dst,
        int* __restrict__ cursor, int* __restrict__ colsrc, int E) {
    int e = blockIdx.x * blockDim.x + threadIdx.x;
    if (e < E) {
        int slot = atomicAdd(&cursor[dst[e]], 1);
        colsrc[slot] = src[e];
    }
}

// ---------------------------------------------------------------- weight prep
// Transposed f16 planes Bt[n][k] for the 8 hidden-dim weight matrices.
struct WPtrs { const float* w[8]; };

__global__ __launch_bounds__(256) void convw_kernel(WPtrs wp, _Float16* __restrict__ btf) {
    __shared__ _Float16 S[64][72];
    int mat = blockIdx.y;
    int tk = blockIdx.x >> 2, tn = blockIdx.x & 3;  // 64x64 tile
    const float* W = wp.w[mat];
    int kr = threadIdx.x >> 2, nc = (threadIdx.x & 3) * 16;
    const float* p = W + (size_t)(tk * 64 + kr) * 256 + tn * 64 + nc;
#pragma unroll
    for (int i = 0; i < 16; i++) S[nc + i][kr] = (_Float16)p[i];
    __syncthreads();
    int nr = threadIdx.x >> 2, kc = (threadIdx.x & 3) * 16;
    size_t ob = (size_t)mat * 65536 + (size_t)(tn * 64 + nr) * 256 + tk * 64 + kc;
#pragma unroll
    for (int i = 0; i < 16; i++) btf[ob + i] = S[nr][kc + i];
}

// ---------------------------------------------------------------- x -> f16
__global__ __launch_bounds__(256) void xcvt_kernel(const float* __restrict__ x,
        _Float16* __restrict__ xh, int n8) {
    int i = blockIdx.x * 256 + threadIdx.x;
    if (i < n8) {
        f32x4 a = *(const f32x4*)(x + (size_t)i * 8);
        f32x4 b = *(const f32x4*)(x + (size_t)i * 8 + 4);
        f16x8 h;
#pragma unroll
        for (int j = 0; j < 4; j++) { h[j] = (_Float16)a[j]; h[j + 4] = (_Float16)b[j]; }
        *(f16x8*)(xh + (size_t)i * 8) = h;
    }
}

// ---------------------------------------------------------------- GEMM (f16 MFMA, m97-style)
// C[Mpad,256](f16) = act(A[Mpad,256](f16) @ W + bias); Bt[n][k] f16 transposed plane.
// BM=128, BN=64, BK=64; 256 thr = 4 waves (2x2), wave tile 64x32.
// A-tile 128x[128B] + B-tile 64x[128B] in LDS, global_load_lds staged,
// XOR-swizzle: phys 16B slot = logical ^ (row&7), applied at BOTH stage-src and read.

template<int ACT>
__global__ __launch_bounds__(256, 4) void gemm_kernel(
        const _Float16* __restrict__ A, const _Float16* __restrict__ Bt,
        const float* __restrict__ bias, unsigned short* __restrict__ C) {
    __shared__ __align__(16) char As[128 * 128];  // 16 KB
    __shared__ __align__(16) char Bs[64 * 128];   //  8 KB
    const int tid = threadIdx.x;
    const int wave = tid >> 6, lane = tid & 63;
    const int row0 = blockIdx.x * 128, col0 = blockIdx.y * 64;
    const int wm = wave >> 1, wn = wave & 1;
    const int lr = lane & 15;
    const int lsub = lane >> 3, lslot = lane & 7;  // staging: 8 lanes/row

    f32x4 acc[4][2];
#pragma unroll
    for (int m = 0; m < 4; m++)
#pragma unroll
        for (int n = 0; n < 2; n++) acc[m][n] = (f32x4)0.0f;

    for (int k0 = 0; k0 < 256; k0 += 64) {
        // ---- stage A (16 chunks) + B (8 chunks); 1 KB per chunk, 6 chunks/wave
#pragma unroll
        for (int c6 = 0; c6 < 6; ++c6) {
            int chunk = wave * 6 + c6;  // wave-uniform
            const _Float16* gp;
            char* lp;
            if (chunk < 16) {
                int r = chunk * 8 + lsub;
                gp = A + (size_t)(row0 + r) * 256 + k0 + (lslot ^ (r & 7)) * 8;
                lp = As + chunk * 1024;
            } else {
                int r = (chunk - 16) * 8 + lsub;
                gp = Bt + (size_t)(col0 + r) * 256 + k0 + (lslot ^ (r & 7)) * 8;
                lp = Bs + (chunk - 16) * 1024;
            }
            gld16(gp, lp + lane * 16);
        }
        __syncthreads();

        // ---- compute: 2 sub-K of 32
#pragma unroll
        for (int kk = 0; kk < 2; ++kk) {
            const int kb = kk * 64 + (lane >> 4) * 16;  // byte offset of logical 16B slot
            f16x8 af[4], bf[2];
#pragma unroll
            for (int m = 0; m < 4; ++m) {
                int r = wm * 64 + m * 16 + lr;
                af[m] = *(const f16x8*)(As + r * 128 + (kb ^ ((r & 7) << 4)));
            }
#pragma unroll
            for (int n = 0; n < 2; ++n) {
                int r = wn * 32 + n * 16 + lr;
                bf[n] = *(const f16x8*)(Bs + r * 128 + (kb ^ ((r & 7) << 4)));
            }
#pragma unroll
            for (int m = 0; m < 4; ++m)
#pragma unroll
                for (int n = 0; n < 2; ++n)
                    acc[m][n] = __builtin_amdgcn_mfma_f32_16x16x32_f16(af[m], bf[n], acc[m][n], 0, 0, 0);
        }
        __syncthreads();
    }

    // ---- epilogue: C/D layout col=lane&15, row=(lane>>4)*4+j (buffers row-padded, no guard)
#pragma unroll
    for (int m = 0; m < 4; ++m) {
        int rb = row0 + wm * 64 + m * 16 + (lane >> 4) * 4;
#pragma unroll
        for (int n = 0; n < 2; ++n) {
            int col = col0 + wn * 32 + n * 16 + lr;
            float bv = bias ? bias[col] : 0.0f;
#pragma unroll
            for (int j = 0; j < 4; ++j) {
                float xv = acc[m][n][j] + bv;
                if (ACT) xv = xv > 0.0f ? xv : expm1f(xv);
                C[(size_t)(rb + j) * 256 + col] = ftof16(xv);
            }
        }
    }
}

// ---------------------------------------------------------------- aggregation
// h f16 [*,256]; out f16. 256 threads = 4 waves = 4 nodes; per-wave LDS staging,
// no block barriers. Each lane: 4 feats via uint2 gathers.
__global__ __launch_bounds__(256) void agg_kernel(const unsigned short* __restrict__ h,
        const float* __restrict__ dinv, const int* __restrict__ rowptr,
        const int* __restrict__ colsrc, const float* __restrict__ bias,
        unsigned short* __restrict__ out, int doLN, const float* __restrict__ g,
        const float* __restrict__ lb, int N) {
    __shared__ int2 se[4][64];
    const int w = threadIdx.x >> 6, lane = threadIdx.x & 63;
    const int node = blockIdx.x * 4 + w;
    if (node >= N) return;
    const float di = dinv[node];
    const float dd = di * di;
    const int j0 = lane * 4;

    uint2 us = *(const uint2*)(h + (size_t)node * 256 + j0);
    float acc0 = f16tof((unsigned short)(us.x & 0xFFFF)) * dd;
    float acc1 = f16tof((unsigned short)(us.x >> 16)) * dd;
    float acc2 = f16tof((unsigned short)(us.y & 0xFFFF)) * dd;
    float acc3 = f16tof((unsigned short)(us.y >> 16)) * dd;

    const int s0 = rowptr[node], s1 = rowptr[node + 1];
    for (int base = s0; base < s1; base += 64) {
        int cnt = min(64, s1 - base);
        if (lane < cnt) {
            int s = colsrc[base + lane];
            se[w][lane] = make_int2(s, __float_as_int(dinv[s] * di));
        }
#pragma unroll 4
        for (int i = 0; i < cnt; i++) {
            int2 e = se[w][i];
            uint2 uu = *(const uint2*)(h + (size_t)e.x * 256 + j0);
            float wt = __int_as_float(e.y);
            acc0 = fmaf(f16tof((unsigned short)(uu.x & 0xFFFF)), wt, acc0);
            acc1 = fmaf(f16tof((unsigned short)(uu.x >> 16)), wt, acc1);
            acc2 = fmaf(f16tof((unsigned short)(uu.y & 0xFFFF)), wt, acc2);
            acc3 = fmaf(f16tof((unsigned short)(uu.y >> 16)), wt, acc3);
        }
    }

    f32x4 bv = *(const f32x4*)(bias + j0);
    acc0 += bv[0]; acc1 += bv[1]; acc2 += bv[2]; acc3 += bv[3];
    acc0 = acc0 > 0.0f ? acc0 : expm1f(acc0);
    acc1 = acc1 > 0.0f ? acc1 : expm1f(acc1);
    acc2 = acc2 > 0.0f ? acc2 : expm1f(acc2);
    acc3 = acc3 > 0.0f ? acc3 : expm1f(acc3);

    if (doLN) {
        float v = acc0 + acc1 + acc2 + acc3;
#pragma unroll
        for (int off = 32; off; off >>= 1) v += __shfl_xor(v, off, 64);
        float mu = v * (1.0f / 256.0f);
        float d0 = acc0 - mu, d1 = acc1 - mu, d2 = acc2 - mu, d3 = acc3 - mu;
        float q = d0 * d0 + d1 * d1 + d2 * d2 + d3 * d3;
#pragma unroll
        for (int off = 32; off; off >>= 1) q += __shfl_xor(q, off, 64);
        float rs = rsqrtf(q * (1.0f / 256.0f) + 1e-5f);
        f32x4 gv = *(const f32x4*)(g + j0);
        f32x4 lv = *(const f32x4*)(lb + j0);
        acc0 = d0 * rs * gv[0] + lv[0];
        acc1 = d1 * rs * gv[1] + lv[1];
        acc2 = d2 * rs * gv[2] + lv[2];
        acc3 = d3 * rs * gv[3] + lv[3];
    }

    unsigned lo = (unsigned)ftof16(acc0) | ((unsigned)ftof16(acc1) << 16);
    unsigned hi = (unsigned)ftof16(acc2) | ((unsigned)ftof16(acc3) << 16);
    *(uint2*)(out + (size_t)node * 256 + j0) = make_uint2(lo, hi);
}

// ---------------------------------------------------------------- final head
__global__ __launch_bounds__(256) void final_kernel(const unsigned short* __restrict__ x,
        const float* __restrict__ W, const float* __restrict__ b,
        float* __restrict__ out, int M) {
    __shared__ float sW[256 * 25];
    for (int i = threadIdx.x; i < 256 * 25; i += 256) sW[i] = W[i];
    __syncthreads();
    int group = threadIdx.x >> 5;  // 8 nodes per block
    int c = threadIdx.x & 31;
    int node = blockIdx.x * 8 + group;
    if (node >= M || c >= 25) return;
    const uint2* xr = (const uint2*)(x + (size_t)node * 256);
    float acc = b[c];
#pragma unroll 8
    for (int k4 = 0; k4 < 64; k4++) {
        uint2 v = xr[k4];
        int k = k4 * 4;
        acc = fmaf(f16tof((unsigned short)(v.x & 0xFFFF)), sW[(k + 0) * 25 + c],
              fmaf(f16tof((unsigned short)(v.x >> 16)),   sW[(k + 1) * 25 + c],
              fmaf(f16tof((unsigned short)(v.y & 0xFFFF)), sW[(k + 2) * 25 + c],
              fmaf(f16tof((unsigned short)(v.y >> 16)),    sW[(k + 3) * 25 + c], acc))));
    }
    out[(size_t)node * 25 + c] = 1.0f / (1.0f + expf(-acc));
}

// ---------------------------------------------------------------- launch

extern "C" void kernel_launch(void* const* d_in, const int* in_sizes, int n_in,
                              void* d_out, int out_size, void* d_ws, size_t ws_size,
                              hipStream_t stream) {
    const float* x       = (const float*)d_in[0];
    const int*   ei      = (const int*)d_in[1];
    const float* W_mlp   = (const float*)d_in[2];
    const float* b_mlp   = (const float*)d_in[3];
    const float* W_conv1 = (const float*)d_in[4];
    const float* b_conv1 = (const float*)d_in[5];
    const float* W_hid   = (const float*)d_in[6];
    const float* b_hid   = (const float*)d_in[7];
    const float* ln_g    = (const float*)d_in[8];
    const float* ln_b    = (const float*)d_in[9];
    const float* W_post  = (const float*)d_in[10];
    const float* b_post  = (const float*)d_in[11];
    const float* W_lin   = (const float*)d_in[12];
    const float* b_lin   = (const float*)d_in[13];
    float* out = (float*)d_out;

    const int N = in_sizes[0] / HID;   // 50000
    const int E = in_sizes[1] / 2;     // 800000
    const int* src = ei;
    const int* dst = ei + E;
    const int NB = (N + 255) / 256;
    const int Mpad = (N + 127) & ~127; // 50048 (row-padded activation buffers)

    // workspace layout (f16 activations, padded rows)
    unsigned short* buf0 = (unsigned short*)d_ws;              // Mpad*256 f16
    unsigned short* buf1 = buf0 + (size_t)Mpad * HID;          // Mpad*256 f16
    _Float16* xh  = (_Float16*)(buf1 + (size_t)Mpad * HID);    // Mpad*256 f16
    float* dinv   = (float*)(xh + (size_t)Mpad * HID);         // N
    int*   deg    = (int*)(dinv + N);                          // N
    int*   rowptr = deg + N;                                   // N+1
    int*   cursor = rowptr + N + 1;                            // N
    int*   colsrc = cursor + N;                                // E
    int*   incl   = colsrc + E;                                // N
    int*   bsum   = incl + N;                                  // <=256
    uintptr_t bp  = ((uintptr_t)(bsum + 256) + 255) & ~(uintptr_t)255;
    _Float16* btf = (_Float16*)bp;                             // 8*65536 f16, 256B-aligned

    // ---- weight prep (8 matrices -> transposed f16 planes)
    WPtrs wp;
    wp.w[0] = W_mlp;
    wp.w[1] = W_mlp + 65536;
    wp.w[2] = W_conv1;
    wp.w[3] = W_hid;
    wp.w[4] = W_hid + 65536;
    wp.w[5] = W_hid + 2 * 65536;
    wp.w[6] = W_post;
    wp.w[7] = W_post + 65536;
    convw_kernel<<<dim3(16, 8), 256, 0, stream>>>(wp, btf);

    // ---- x -> f16
    xcvt_kernel<<<(N * HID / 8 + 255) / 256, 256, 0, stream>>>(x, xh, N * HID / 8);

    // ---- edge prep
    hipMemsetAsync(deg, 0, (size_t)N * sizeof(int), stream);
    hist_kernel<<<(E + 255) / 256, 256, 0, stream>>>(dst, deg, E);
    scan1_kernel<<<NB, 256, 0, stream>>>(deg, incl, bsum, N);
    scan2_kernel<<<1, 256, 0, stream>>>(bsum, NB);
    scan3_kernel<<<NB + 1, 256, 0, stream>>>(deg, incl, bsum, rowptr, cursor, dinv, N, E);
    fill_kernel<<<(E + 255) / 256, 256, 0, stream>>>(src, dst, cursor, colsrc, E);

    dim3 gg(Mpad / 128, 4);
    const size_t WM = 65536;
    const _Float16* f0 = (const _Float16*)buf0;
    const _Float16* f1 = (const _Float16*)buf1;

    // ---- pre-MLP: xh -> buf1 -> buf0 (celu)
    gemm_kernel<1><<<gg, 256, 0, stream>>>(xh, btf + 0 * WM, b_mlp,       buf1);
    gemm_kernel<1><<<gg, 256, 0, stream>>>(f1, btf + 1 * WM, b_mlp + 256, buf0);

    // ---- conv1: h = buf0@Wc -> buf1, agg -> buf0 (celu, no LN)
    gemm_kernel<0><<<gg, 256, 0, stream>>>(f0, btf + 2 * WM, nullptr, buf1);
    agg_kernel<<<(N + 3) / 4, 256, 0, stream>>>(buf1, dinv, rowptr, colsrc, b_conv1, buf0, 0, nullptr, nullptr, N);

    // ---- hidden convs: buf0 -> buf1 -> buf0 (celu + LN)
    for (int i = 0; i < 3; i++) {
        gemm_kernel<0><<<gg, 256, 0, stream>>>(f0, btf + (size_t)(3 + i) * WM, nullptr, buf1);
        agg_kernel<<<(N + 3) / 4, 256, 0, stream>>>(buf1, dinv, rowptr, colsrc, b_hid + i * 256, buf0, 1, ln_g, ln_b, N);
    }

    // ---- post-MLP: buf0 -> buf1 -> buf0 (celu)
    gemm_kernel<1><<<gg, 256, 0, stream>>>(f0, btf + 6 * WM, b_post,       buf1);
    gemm_kernel<1><<<gg, 256, 0, stream>>>(f1, btf + 7 * WM, b_post + 256, buf0);

    // ---- head + sigmoid
    final_kernel<<<(N + 7) / 8, 256, 0, stream>>>(buf0, W_lin, b_lin, out, N);
    (void)ws_size; (void)n_in; (void)out_size;
}